// Round 10
// baseline (276.654 us; speedup 1.0000x reference)
//
#include <hip/hip_runtime.h>
#include <math.h>

#define NPTS 262144
#define KC 512
#define DD 64
#define MARGIN 1e-3f
#define LOSCALE 2048.0f
#define INV2LO 0.0009765625f   // 2 / LOSCALE = 2^-10
#define SLICE 128              // == points/block -> llist cannot overflow

typedef _Float16 f16x8 __attribute__((ext_vector_type(8)));
typedef _Float16 f16x4 __attribute__((ext_vector_type(4)));
typedef float f32x4 __attribute__((ext_vector_type(4)));

__device__ __forceinline__ float csq_pairwise8(const float* row) {
    float r[8];
#pragma unroll
    for (int t = 0; t < 8; ++t) r[t] = __fmul_rn(row[t], row[t]);
#pragma unroll
    for (int b = 1; b < 8; ++b)
#pragma unroll
        for (int t = 0; t < 8; ++t)
            r[t] = __fadd_rn(r[t], __fmul_rn(row[8 * b + t], row[8 * b + t]));
    return __fadd_rn(__fadd_rn(__fadd_rn(r[0], r[1]), __fadd_rn(r[2], r[3])),
                     __fadd_rn(__fadd_rn(r[4], r[5]), __fadd_rn(r[6], r[7])));
}

__global__ __launch_bounds__(256) void prep_kernel(const float* __restrict__ c,
                                                   float* __restrict__ out_c,
                                                   float* __restrict__ csq) {
    int j = blockIdx.x * 256 + threadIdx.x;
    if (j < KC * DD) out_c[j] = c[j];
    if (j < KC) csq[j] = csq_pairwise8(c + j * DD);
}

// SINGLE-PASS structure. All 512 centroids staged (hi+lo, 128 KB dynamic LDS)
// BEFORE the A-fragments are loaded: the staging pressure spike coexists with
// NO persistent state, so the allocator has nothing to spill (R6-R9: 94 MB
// scratch WRITE = frags+best2 spilled around each pass's staging spike).
// LDS-bound at 1 block/CU (4 waves) -> per-wave register budget is huge; no
// waves-per-eu hint so the allocator uses headroom instead of scratch.
__global__ __launch_bounds__(256) void approx_kernel(const float* __restrict__ x,
                                                     const float* __restrict__ c,
                                                     const float* __restrict__ csq,
                                                     float* __restrict__ out_assign) {
    extern __shared__ char smem[];          // [0,64K) c_hi | [64K,128K) c_lo'
    __shared__ float scs[KC];
    __shared__ int llist[SLICE];
    __shared__ int lcnt;

    int tid = threadIdx.x;
    if (tid == 0) lcnt = 0;
    scs[tid] = csq[tid];
    scs[tid + 256] = csq[tid + 256];

    int wid = tid >> 6, lane = tid & 63;
    int lrow = lane & 15, lgrp = lane >> 4;
    int pbase = blockIdx.x * 128 + wid * 32;

    // ---- Stage ALL 512 centroid rows: fp32 -> (hi, lo') f16, XOR-swizzled
    // (swizzle proven absmax=0 in R4-R9). Unroll 8 caps in-flight regs ~35.
    const float4* csrc = (const float4*)c;
#pragma unroll 8
    for (int it = 0; it < 32; ++it) {
        int chunk = tid + it * 256;                 // 8192 x 16B-src chunks
        int row = chunk >> 4, q = chunk & 15;
        float4 v = csrc[chunk];
        f16x4 h, l;
        _Float16 t;
        t = (_Float16)v.x; h[0] = t; l[0] = (_Float16)((v.x - (float)t) * LOSCALE);
        t = (_Float16)v.y; h[1] = t; l[1] = (_Float16)((v.y - (float)t) * LOSCALE);
        t = (_Float16)v.z; h[2] = t; l[2] = (_Float16)((v.z - (float)t) * LOSCALE);
        t = (_Float16)v.w; h[3] = t; l[3] = (_Float16)((v.w - (float)t) * LOSCALE);
        int off = row * 128 + (((q >> 1) ^ (row & 7)) << 4) + (q & 1) * 8;
        *(f16x4*)(smem + off) = h;
        *(f16x4*)(smem + 65536 + off) = l;
    }
    __syncthreads();

    // ---- NOW load A fragments (layout proven absmax=0 R4-R9): row=lane&15,
    // k-elems kk*32+lgrp*8. Split x = hi + lo'/2048 (lo' f16-normal).
    f16x8 ahi[2][2], alo[2][2];
#pragma unroll
    for (int s = 0; s < 2; ++s)
#pragma unroll
        for (int kk = 0; kk < 2; ++kk) {
            const float4* p = (const float4*)(x + (size_t)(pbase + s * 16 + lrow) * DD
                                              + kk * 32 + lgrp * 8);
            float4 u0 = p[0], u1 = p[1];
            float f[8] = {u0.x, u0.y, u0.z, u0.w, u1.x, u1.y, u1.z, u1.w};
            f16x8 h, l;
#pragma unroll
            for (int e = 0; e < 8; ++e) {
                _Float16 hh = (_Float16)f[e];
                h[e] = hh;
                l[e] = (_Float16)((f[e] - (float)hh) * LOSCALE);
            }
            ahi[s][kk] = h;
            alo[s][kk] = l;
        }

    float b1[2][4], b2[2][4];
    int k1[2][4];
#pragma unroll
    for (int s = 0; s < 2; ++s)
#pragma unroll
        for (int r = 0; r < 4; ++r) { b1[s][r] = INFINITY; b2[s][r] = INFINITY; k1[s][r] = 0; }

    // ---- Single 32-iteration MFMA loop over all 512 centroids.
    int base0 = lrow * 128 + ((lgrp ^ (lrow & 7)) << 4);
    int csi = lrow;
#pragma unroll 2
    for (int ct = 0; ct < 32; ++ct) {
        f16x8 bh0 = *(const f16x8*)(smem + base0);
        f16x8 bh1 = *(const f16x8*)(smem + (base0 ^ 64));
        f16x8 bl0 = *(const f16x8*)(smem + 65536 + base0);
        f16x8 bl1 = *(const f16x8*)(smem + 65536 + (base0 ^ 64));
        float cs = scs[csi];
        int kv = csi;
#pragma unroll
        for (int s = 0; s < 2; ++s) {
            f32x4 hh = {0.f, 0.f, 0.f, 0.f}, cr = {0.f, 0.f, 0.f, 0.f};
            hh = __builtin_amdgcn_mfma_f32_16x16x32_f16(ahi[s][0], bh0, hh, 0, 0, 0);
            hh = __builtin_amdgcn_mfma_f32_16x16x32_f16(ahi[s][1], bh1, hh, 0, 0, 0);
            cr = __builtin_amdgcn_mfma_f32_16x16x32_f16(ahi[s][0], bl0, cr, 0, 0, 0);
            cr = __builtin_amdgcn_mfma_f32_16x16x32_f16(ahi[s][1], bl1, cr, 0, 0, 0);
            cr = __builtin_amdgcn_mfma_f32_16x16x32_f16(alo[s][0], bh0, cr, 0, 0, 0);
            cr = __builtin_amdgcn_mfma_f32_16x16x32_f16(alo[s][1], bh1, cr, 0, 0, 0);
#pragma unroll
            for (int r = 0; r < 4; ++r) {
                float d = __fmaf_rn(-INV2LO, cr[r], __fmaf_rn(-2.0f, hh[r], cs));
                bool lt = d < b1[s][r];
                b2[s][r] = fminf(b2[s][r], fmaxf(b1[s][r], d));
                b1[s][r] = fminf(b1[s][r], d);
                k1[s][r] = lt ? kv : k1[s][r];
            }
        }
        base0 += 2048;
        csi += 16;
    }

    // Merge best-2 across the 16 lanes of each row-group (ties -> gap 0 ->
    // flagged -> exact rescore, so tie direction is free).
#pragma unroll
    for (int dd = 1; dd < 16; dd <<= 1)
#pragma unroll
        for (int s = 0; s < 2; ++s)
#pragma unroll
            for (int r = 0; r < 4; ++r) {
                float o1 = __shfl_xor(b1[s][r], dd);
                float o2 = __shfl_xor(b2[s][r], dd);
                int ok = __shfl_xor(k1[s][r], dd);
                b2[s][r] = fminf(fminf(b2[s][r], o2), fmaxf(b1[s][r], o1));
                bool lt = o1 < b1[s][r];
                b1[s][r] = fminf(b1[s][r], o1);
                k1[s][r] = lt ? ok : k1[s][r];
            }

    // Flag phase (LDS only; SLICE == points/block so no overflow; fallback
    // write keeps single-writer semantics regardless).
    if (lrow == 0) {
#pragma unroll
        for (int s = 0; s < 2; ++s)
#pragma unroll
            for (int r = 0; r < 4; ++r) {
                int p = pbase + s * 16 + lgrp * 4 + r;   // C/D row=(lane>>4)*4+reg
                if (b2[s][r] - b1[s][r] <= MARGIN) {
                    int t = atomicAdd(&lcnt, 1);
                    if (t < SLICE) llist[t] = p;
                    else out_assign[p] = (float)k1[s][r];
                } else {
                    out_assign[p] = (float)k1[s][r];
                }
            }
    }
    __syncthreads();

    // In-kernel exact rescore: one wave per flagged point, lanes own 8
    // centroids. Bit-identical np-replica distance (proven absmax=0 R1-R9).
    // First-index-wins via packed (distbits<<32)|k min (dist > 0 always).
    int n = lcnt;
    if (n > SLICE) n = SLICE;
    for (int t = wid; t < n; t += 4) {
        int i = __builtin_amdgcn_readfirstlane(llist[t]);
        const float* xr = x + (size_t)i * DD;   // wave-uniform -> s_loads

        float r8[8];
#pragma unroll
        for (int e = 0; e < 8; ++e) r8[e] = __fmul_rn(xr[e], xr[e]);
#pragma unroll
        for (int blk = 1; blk < 8; ++blk)
#pragma unroll
            for (int e = 0; e < 8; ++e)
                r8[e] = __fadd_rn(r8[e], __fmul_rn(xr[8 * blk + e], xr[8 * blk + e]));
        float x_sq = __fadd_rn(__fadd_rn(__fadd_rn(r8[0], r8[1]), __fadd_rn(r8[2], r8[3])),
                               __fadd_rn(__fadd_rn(r8[4], r8[5]), __fadd_rn(r8[6], r8[7])));

        unsigned long long best = ~0ull;
#pragma unroll
        for (int j = 0; j < 8; ++j) {
            int k = j * 64 + lane;
            const float* crow = c + (size_t)k * DD;
            float a0 = 0.f, a1 = 0.f, a2 = 0.f, a3 = 0.f;
#pragma unroll
            for (int d = 0; d < DD; d += 4) {
                a0 = __fmaf_rn(xr[d + 0], crow[d + 0], a0);
                a1 = __fmaf_rn(xr[d + 1], crow[d + 1], a1);
                a2 = __fmaf_rn(xr[d + 2], crow[d + 2], a2);
                a3 = __fmaf_rn(xr[d + 3], crow[d + 3], a3);
            }
            float acc = __fadd_rn(__fadd_rn(a0, a1), __fadd_rn(a2, a3));
            float tt = __fadd_rn(x_sq, csq[k]);
            float dist = __fmaf_rn(-2.0f, acc, tt);
            unsigned long long key =
                ((unsigned long long)__float_as_uint(dist) << 32) | (unsigned)k;
            best = best < key ? best : key;
        }
#pragma unroll
        for (int dd = 1; dd < 64; dd <<= 1) {
            unsigned hi = (unsigned)__shfl_xor((int)(best >> 32), dd);
            unsigned lo = (unsigned)__shfl_xor((int)(best & 0xFFFFFFFFull), dd);
            unsigned long long o = ((unsigned long long)hi << 32) | lo;
            best = best < o ? best : o;
        }
        if (lane == 0) out_assign[i] = (float)(unsigned)(best & 0xFFFFFFFFull);
    }
}

extern "C" void kernel_launch(void* const* d_in, const int* in_sizes, int n_in,
                              void* d_out, int out_size, void* d_ws, size_t ws_size,
                              hipStream_t stream) {
    const float* x = (const float*)d_in[0];
    const float* c = (const float*)d_in[1];
    float* out = (float*)d_out;
    float* out_assign = out + KC * DD;
    float* csq = (float*)d_ws;   // 2 KB of d_ws, nothing else

    prep_kernel<<<(KC * DD + 255) / 256, 256, 0, stream>>>(c, out, csq);
    approx_kernel<<<NPTS / 128, 256, 131072, stream>>>(x, c, csq, out_assign);
}